// Round 1
// baseline (884.212 us; speedup 1.0000x reference)
//
#include <hip/hip_runtime.h>

// CTC total-score forward (log-semiring), B=32 T=800 C=5000 L=100, S=201.
//
// Two-kernel split:
//   1) ctc_gather: grid-wide scattered gather of the <=101 needed classes per
//      (b,t) row into a dense compressed workspace ws[B][T][RP]
//      (RP=104: [0..99]=targets, [100]=blank, [101..103]=NEGV pad).
//      Spreads the ~2.6M 4B gathers over all 256 CUs instead of 32.
//   2) ctc_alpha: serial alpha recursion, one block (1 consumer wave +
//      4 producer waves) per batch element. Producers now stream DENSE
//      coalesced float4 rows from ws into a double-buffered LDS ring;
//      consumer math identical to the verified fused kernel.
// Falls back to the original fused kernel if ws_size is too small.

constexpr int B  = 32;
constexpr int T  = 800;
constexpr int C  = 5000;
constexpr int L  = 100;
constexpr int S  = 2 * L + 1;    // 201
constexpr float NEGV = -1e30f;

// compressed emission row
constexpr int RP  = 104;         // 104*4 = 416 B, 16B-aligned rows
constexpr int CH  = 64;          // timesteps per LDS chunk in alpha kernel
constexpr int CHE = CH * RP;     // 6656 floats = 26,624 B per buffer
constexpr int BLK = 320;         // 1 consumer wave + 4 producer waves
constexpr int NPROD = 256;
constexpr int GCH = 32;          // t-rows per gather block
constexpr size_t WS_NEED = (size_t)B * T * RP * sizeof(float);

__device__ __forceinline__ float lse2(float a, float b) {
    const float m = fmaxf(a, b);
    return m + __logf(__expf(a - m) + __expf(b - m));
}
__device__ __forceinline__ float lse3(float a, float b, float c) {
    const float m = fmaxf(a, fmaxf(b, c));
    return m + __logf(__expf(a - m) + __expf(b - m) + __expf(c - m));
}

// ---------------------------------------------------------------------------
// Kernel 1: scattered gather -> dense compressed rows, all CUs.
// grid (B, T/GCH), 128 threads. Thread j owns row-slot j for GCH timesteps:
// fixed class, 32 independent loads (stride C) -> deep MLP, per-wave footprint
// is one 20KB row (L1-friendly). Writes are lane-consecutive (coalesced).
// ---------------------------------------------------------------------------
__global__ __launch_bounds__(128) void ctc_gather(
    const float* __restrict__ lp, const int* __restrict__ targets,
    const int* __restrict__ il_, float* __restrict__ ws)
{
    __shared__ int tgt[L];
    const int b  = blockIdx.x;
    const int t0 = blockIdx.y * GCH;
    const int j  = threadIdx.x;
    if (j < L) tgt[j] = targets[b * L + j];
    __syncthreads();

    const int il   = il_[b];
    const int rows = ((il - t0) < GCH) ? (il - t0) : GCH;
    if (rows <= 0 || j >= RP) return;

    float* __restrict__ dst = ws + ((size_t)b * T + t0) * RP + j;

    if (j > 100) {                      // pad slots: never read, keep finite-ish
#pragma unroll
        for (int i = 0; i < GCH; ++i)
            if (i < rows) dst[(size_t)i * RP] = NEGV;
        return;
    }
    const int cls = (j < 100) ? tgt[j] : 0;   // j==100 -> blank
    const float* __restrict__ sp = lp + ((size_t)b * T + t0) * C + cls;

    if (rows == GCH) {
#pragma unroll 8
        for (int i = 0; i < GCH; ++i)
            dst[(size_t)i * RP] = sp[(size_t)i * C];
    } else {
        for (int i = 0; i < rows; ++i)
            dst[(size_t)i * RP] = sp[(size_t)i * C];
    }
}

// ---------------------------------------------------------------------------
// Kernel 2: serial alpha recursion over dense ws rows.
// ---------------------------------------------------------------------------
__global__ __launch_bounds__(BLK) void ctc_alpha(
    const float* __restrict__ ws, const int* __restrict__ targets,
    const int* __restrict__ il_, const int* __restrict__ tl_,
    float* __restrict__ out)
{
    __shared__ float buf[2][CHE];   // 53,248 B
    __shared__ int   tgt[L];
    __shared__ float sm[256];

    const int b   = blockIdx.x;
    const int tid = threadIdx.x;
    const int il  = il_[b];
    const int nch = (il + CH - 1) / CH;
    const float* __restrict__ base = ws + (size_t)b * T * RP;

    if (tid < L) tgt[tid] = targets[b * L + tid];
    __syncthreads();

    // ---- consumer-wave constants (wave 0) ----
    const int lane = tid;
    const int s0   = 4 * lane;
    bool skip1 = false, skip3 = false;
    bool v0 = false, v1 = false, v2c = false, v3 = false;
    int  offt = 0;
    if (tid < 64) {
        const int l2 = 2 * lane;
        const int i1 = (l2     < L) ? l2     : L - 1;
        const int i3 = (l2 + 1 < L) ? l2 + 1 : L - 1;
        const int ip = (l2 - 1 >= 0) ? l2 - 1 : 0;
        const int c1i = tgt[i1], c3i = tgt[i3], cpi = tgt[ip];
        skip1 = (lane == 0) ? true : (c1i != cpi);
        skip3 = (c3i != c1i);
        v0  = (s0     < S);
        v1  = (s0 + 1 < S);
        v2c = (s0 + 2 < S);
        v3  = (s0 + 3 < S);
        offt = (l2 <= 100) ? l2 : 100;   // even -> float2 (8B) aligned
    }

    float a0 = NEGV, a1v = NEGV, a2v = NEGV, a3v = NEGV;

    // ---- chunk loop: c = -1 is the producer prologue (fill chunk 0) ----
    for (int c = -1; c < nch; ++c) {
        if (tid >= 64) {
            // -------- producers: dense coalesced copy of chunk c+1 --------
            const int c2 = c + 1;
            if (c2 < nch) {
                const int rows = ((il - c2 * CH) < CH) ? (il - c2 * CH) : CH;
                const int jmax = rows * (RP / 4);            // float4 count
                float4* __restrict__ dst = (float4*)buf[c2 & 1];
                const float4* __restrict__ src =
                    (const float4*)(base + (size_t)c2 * CHE);
                for (int j = tid - 64; j < jmax; j += NPROD) dst[j] = src[j];
            }
        } else if (c >= 0) {
            // -------- consumer: process chunk c --------
            const float* bp = buf[c & 1];
            const int tbase = c * CH;
            const int rmax  = (il - tbase < CH) ? (il - tbase) : CH;
            float2 tv = *(const float2*)(bp + offt);   // targets pair, row 0
            float  bl = bp[100];                       // blank, row 0
            for (int r = 0; r < rmax; ++r) {
                const float2 ctv = tv;
                const float  cbl = bl;
                if (r + 1 < rmax) {
                    tv = *(const float2*)(bp + (r + 1) * RP + offt);
                    bl = bp[(r + 1) * RP + 100];
                }
                const int t = tbase + r;
                if (t == 0) {
                    a0  = (lane == 0) ? cbl   : NEGV;
                    a1v = (lane == 0) ? ctv.x : NEGV;
                    a2v = NEGV; a3v = NEGV;
                } else {
                    float up3 = __shfl_up(a3v, 1);   // state 4l-1
                    if (lane == 0) up3 = NEGV;
                    const float n0 = lse2(a0, up3) + cbl;
                    const float n1 = (skip1 ? lse3(a1v, a0, up3) : lse2(a1v, a0)) + ctv.x;
                    const float n2 = lse2(a2v, a1v) + cbl;
                    const float n3 = (skip3 ? lse3(a3v, a2v, a1v) : lse2(a3v, a2v)) + ctv.y;
                    a0  = v0  ? n0 : NEGV;
                    a1v = v1  ? n1 : NEGV;
                    a2v = v2c ? n2 : NEGV;
                    a3v = v3  ? n3 : NEGV;
                }
            }
        }
        __syncthreads();
    }

    // ---- final extraction (consumer wave) ----
    if (tid < 64) {
        sm[s0 + 0] = a0;
        sm[s0 + 1] = a1v;
        sm[s0 + 2] = a2v;
        sm[s0 + 3] = a3v;
    }
    __syncthreads();

    if (tid == 0) {
        const int tl = tl_[b];
        const float tot = lse2(sm[2 * tl], sm[2 * tl - 1]);
        const bool finite = tot > (NEGV * 0.5f);
        atomicAdd(out + 0, finite ? tot : 0.0f);
        atomicAdd(out + 1, finite ? (float)il : 0.0f);
        atomicAdd(out + 2, (float)il);
    }
}

// ---------------------------------------------------------------------------
// Fallback: original fused kernel (used only if ws_size < WS_NEED).
// ---------------------------------------------------------------------------
constexpr int SPF  = 204;
constexpr int CHF  = 32;
constexpr int CHEF = CHF * SPF;   // 6528

__global__ __launch_bounds__(BLK) void ctc_fused(
    const float* __restrict__ lp, const int* __restrict__ targets,
    const int* __restrict__ il_, const int* __restrict__ tl_,
    float* __restrict__ out)
{
    __shared__ float buf[2][CHEF];
    __shared__ int   tgt[L];
    __shared__ float sm[256];

    const int b   = blockIdx.x;
    const int tid = threadIdx.x;
    const int il  = il_[b];
    const int nch = (il + CHF - 1) / CHF;
    const float* __restrict__ base = lp + (size_t)b * T * C;

    if (tid < L) tgt[tid] = targets[b * L + tid];
    __syncthreads();

    const int lane = tid;
    const int s0   = 4 * lane;
    bool skip1 = false, skip3 = false;
    bool v0 = false, v1 = false, v2c = false, v3 = false;
    int  off = 0;
    if (tid < 64) {
        const int l2 = 2 * lane;
        const int i1 = (l2     < L) ? l2     : L - 1;
        const int i3 = (l2 + 1 < L) ? l2 + 1 : L - 1;
        const int ip = (l2 - 1 >= 0) ? l2 - 1 : 0;
        const int c1i = tgt[i1], c3i = tgt[i3], cpi = tgt[ip];
        skip1 = (lane == 0) ? true : (c1i != cpi);
        skip3 = (c3i != c1i);
        v0  = (s0     < S);
        v1  = (s0 + 1 < S);
        v2c = (s0 + 2 < S);
        v3  = (s0 + 3 < S);
        off = (s0 <= 200) ? s0 : 200;
    }

    float a0 = NEGV, a1v = NEGV, a2v = NEGV, a3v = NEGV;

    for (int c = -1; c < nch; ++c) {
        if (tid >= 64) {
            const int c2 = c + 1;
            if (c2 < nch) {
                float* dst = buf[c2 & 1];
                const int tbase = c2 * CHF;
                const int pid = tid - 64;
#pragma unroll
                for (int bat = 0; bat < 2; ++bat) {
                    float v[13];
                    int   fl[13];
#pragma unroll
                    for (int j = 0; j < 13; ++j) {
                        const int flat = (bat * 13 + j) * NPROD + pid;
                        fl[j] = flat;
                        float val = NEGV;
                        if (flat < CHEF) {
                            const int r = flat / SPF;
                            const int s = flat - r * SPF;
                            const int t = tbase + r;
                            if (t < il) {
                                const int cls = ((s & 1) && s < S) ? tgt[s >> 1] : 0;
                                val = base[(size_t)t * C + cls];
                            }
                        }
                        v[j] = val;
                    }
#pragma unroll
                    for (int j = 0; j < 13; ++j)
                        if (fl[j] < CHEF) dst[fl[j]] = v[j];
                }
            }
        } else if (c >= 0) {
            const float* bp = buf[c & 1];
            const int tbase = c * CHF;
            const int rmax  = (il - tbase < CHF) ? (il - tbase) : CHF;
            float4 e = *(const float4*)(bp + off);
            for (int r = 0; r < rmax; ++r) {
                const float4 cur = e;
                if (r + 1 < rmax) e = *(const float4*)(bp + (r + 1) * SPF + off);
                const int t = tbase + r;
                if (t == 0) {
                    a0  = (lane == 0) ? cur.x : NEGV;
                    a1v = (lane == 0) ? cur.y : NEGV;
                    a2v = NEGV; a3v = NEGV;
                } else {
                    float up3 = __shfl_up(a3v, 1);
                    if (lane == 0) up3 = NEGV;
                    const float n0 = lse2(a0, up3) + cur.x;
                    const float n1 = (skip1 ? lse3(a1v, a0, up3) : lse2(a1v, a0)) + cur.y;
                    const float n2 = lse2(a2v, a1v) + cur.z;
                    const float n3 = (skip3 ? lse3(a3v, a2v, a1v) : lse2(a3v, a2v)) + cur.w;
                    a0  = v0  ? n0 : NEGV;
                    a1v = v1  ? n1 : NEGV;
                    a2v = v2c ? n2 : NEGV;
                    a3v = v3  ? n3 : NEGV;
                }
            }
        }
        __syncthreads();
    }

    if (tid < 64) {
        sm[s0 + 0] = a0;
        sm[s0 + 1] = a1v;
        sm[s0 + 2] = a2v;
        sm[s0 + 3] = a3v;
    }
    __syncthreads();

    if (tid == 0) {
        const int tl = tl_[b];
        const float tot = lse2(sm[2 * tl], sm[2 * tl - 1]);
        const bool finite = tot > (NEGV * 0.5f);
        atomicAdd(out + 0, finite ? tot : 0.0f);
        atomicAdd(out + 1, finite ? (float)il : 0.0f);
        atomicAdd(out + 2, (float)il);
    }
}

extern "C" void kernel_launch(void* const* d_in, const int* in_sizes, int n_in,
                              void* d_out, int out_size, void* d_ws, size_t ws_size,
                              hipStream_t stream)
{
    const float* lp      = (const float*)d_in[0];   // (B,T,C) f32
    const int*   targets = (const int*)d_in[1];     // (B,L)
    const int*   il      = (const int*)d_in[2];     // (B,)
    const int*   tl      = (const int*)d_in[3];     // (B,)
    float* out = (float*)d_out;                     // 3 floats

    hipMemsetAsync(d_out, 0, (size_t)out_size * sizeof(float), stream);

    if (ws_size >= WS_NEED) {
        float* ws = (float*)d_ws;
        ctc_gather<<<dim3(B, T / GCH), 128, 0, stream>>>(lp, targets, il, ws);
        ctc_alpha<<<B, BLK, 0, stream>>>(ws, targets, il, tl, out);
    } else {
        ctc_fused<<<B, BLK, 0, stream>>>(lp, targets, il, tl, out);
    }
}